// Round 16
// baseline (2738.228 us; speedup 1.0000x reference)
//
#include <hip/hip_runtime.h>
#include <hip/hip_bf16.h>
#include <stdint.h>

typedef __hip_bfloat16 bf16;
typedef __attribute__((ext_vector_type(8))) short short8;
typedef __attribute__((ext_vector_type(4))) float f32x4;
typedef __attribute__((ext_vector_type(4))) int i32x4;
typedef __attribute__((ext_vector_type(4))) unsigned int u32x4;

#define NB   64
#define NT   2048
#define NV   32000
#define ND   256
#define NH4  1024
#define NCLS 27
#define CH   256          // time chunk (double-buffered)
#define NCH  (NT / CH)    // 8

// ---------------- dtype conversion / packing ----------------

__global__ __launch_bounds__(256) void k_cvt_embed(const float* __restrict__ e,
                                                   bf16* __restrict__ o) {
  int i = blockIdx.x * blockDim.x + threadIdx.x;
  float4 v = reinterpret_cast<const float4*>(e)[i];
  union { bf16 h[4]; uint2 u; } pk;
  pk.h[0] = __float2bfloat16(v.x);
  pk.h[1] = __float2bfloat16(v.y);
  pk.h[2] = __float2bfloat16(v.z);
  pk.h[3] = __float2bfloat16(v.w);
  reinterpret_cast<uint2*>(o)[i] = pk.u;
}

// Wi [256][1024] f32 -> Wi_t [1024][256] bf16
__global__ __launch_bounds__(256) void k_cvt_wi(const float* __restrict__ wi,
                                                bf16* __restrict__ wit) {
  int i = blockIdx.x * blockDim.x + threadIdx.x;
  int col = i >> 8;
  int k   = i & 255;
  wit[i] = __float2bfloat16(wi[k * NH4 + col]);
}

// per-column scales for i8 quantization of Wh.
__global__ __launch_bounds__(256) void k_scale(const float* __restrict__ wh,
                                               float* __restrict__ dq,
                                               float* __restrict__ rdq,
                                               float* __restrict__ rw) {
  int col = blockIdx.x * 256 + threadIdx.x;   // grid 4
  float m = 0.f;
  for (int k = 0; k < ND; ++k) m = fmaxf(m, fabsf(wh[k * NH4 + col]));
  dq[col]  = m * (1.f / 16129.f);
  rdq[col] = 16129.f / m;
  rw[col]  = 127.f / m;
}

// Wh -> i8 B-fragments for mfma_i32_16x16x64_i8
__global__ __launch_bounds__(256) void k_cvt_whq(const float* __restrict__ wh,
                                                 const float* __restrict__ rw,
                                                 signed char* __restrict__ whq) {
  int idx  = blockIdx.x * 256 + threadIdx.x;  // grid 1024
  int ii   = idx & 15;
  int lane = (idx >> 4) & 63;
  int kq   = (idx >> 10) & 3;
  int nt   = idx >> 12;
  int k   = kq * 64 + (lane >> 4) * 16 + ii;
  int col = nt * 16 + (lane & 15);
  whq[idx] = (signed char)(int)rintf(wh[k * NH4 + col] * rw[col]);
}

// ---------------- gate helpers ----------------
__device__ __forceinline__ float sigf(float x) {
  return __builtin_amdgcn_rcpf(1.f + __expf(-x));
}
__device__ __forceinline__ float tanh_fast(float x) {
  return 1.f - 2.f * __builtin_amdgcn_rcpf(1.f + __expf(2.f * x));
}

// One scan step, in-register gates. Wave wv's n-tiles: nt = q*16 + wv + 8*gs
// (j = q*2+gs) -> its accs hold all 4 gates of units u0 = wv*16+l (gs=0) and
// u1 = (wv+8)*16+l (gs=1), batches = regs 0..1 of lanes 0..15. Read A-frags
// from AR, write h(t+1) frags to AW (double buffer), ONE barrier per step.
#define LSTM_STEP(ZX, AR, AW, ST)                                              \
  {                                                                            \
    i32x4 a0 = *(const i32x4*)&AR[0 * 1024 + l * 16];                          \
    i32x4 a1 = *(const i32x4*)&AR[1 * 1024 + l * 16];                          \
    i32x4 a2 = *(const i32x4*)&AR[2 * 1024 + l * 16];                          \
    i32x4 a3 = *(const i32x4*)&AR[3 * 1024 + l * 16];                          \
    i32x4 acc[8];                                                              \
    _Pragma("unroll")                                                          \
    for (int j = 0; j < 8; ++j) {                                              \
      i32x4 t;                                                                 \
      t = __builtin_amdgcn_mfma_i32_16x16x64_i8(a0, w[j][0], czero, 0, 0, 0);  \
      t = __builtin_amdgcn_mfma_i32_16x16x64_i8(a1, w[j][1], t, 0, 0, 0);      \
      t = __builtin_amdgcn_mfma_i32_16x16x64_i8(a2, w[j][2], t, 0, 0, 0);      \
      acc[j] = __builtin_amdgcn_mfma_i32_16x16x64_i8(a3, w[j][3], t, 0, 0, 0); \
    }                                                                          \
    if (l4 == 0) {                                                             \
      _Pragma("unroll")                                                        \
      for (int gs = 0; gs < 2; ++gs) {                                         \
        _Pragma("unroll")                                                      \
        for (int bb = 0; bb < 2; ++bb) {                                       \
          int s0 = acc[0 * 2 + gs][bb] + ZX[bb * 2 + gs][0];                   \
          int s1 = acc[1 * 2 + gs][bb] + ZX[bb * 2 + gs][1];                   \
          int s2 = acc[2 * 2 + gs][bb] + ZX[bb * 2 + gs][2];                   \
          int s3 = acc[3 * 2 + gs][bb] + ZX[bb * 2 + gs][3];                   \
          float zi  = (float)s0 * dqv[gs][0] + bhv[gs][0];                     \
          float zf  = (float)s1 * dqv[gs][1] + bhv[gs][1];                     \
          float zg_ = (float)s2 * dqv[gs][2] + bhv[gs][2];                     \
          float zo  = (float)s3 * dqv[gs][3] + bhv[gs][3];                     \
          int cc = gs * 2 + bb;                                                \
          c[cc] = sigf(zf) * c[cc] + sigf(zi) * tanh_fast(zg_);                \
          float hv = sigf(zo) * tanh_fast(c[cc]);                              \
          AW[(gs ? kq1 : kq0) * 1024 + (bb + 16 * (gs ? lg1 : lg0)) * 16 + l] =\
              (signed char)(int)rintf(hv * 127.f);                             \
          if ((ST) == CH - 1) hst[(p * 2 + bb) * 256 + (gs ? u1 : u0)] = hv;   \
        }                                                                      \
      }                                                                        \
      if ((ST) + 2 < CH) {                                                     \
        const int* zn = zg + (size_t)((ST) + 2) * 2048;                        \
        _Pragma("unroll")                                                      \
        for (int gs = 0; gs < 2; ++gs)                                         \
          _Pragma("unroll")                                                    \
          for (int bb = 0; bb < 2; ++bb)                                       \
            ZX[bb * 2 + gs] =                                                  \
                *(const i32x4*)(zn + bb * 1024 + (gs ? u1 : u0) * 4);          \
      }                                                                        \
    }                                                                          \
    __syncthreads();                                                           \
  }

// ---------------- fused pipelined kernel ----------------
// Launch L (L = 0..NCH):
//   blocks 0..31   : LSTM-scan chunk L-1 (skip at L==0), reads zx buf (L-1)&1
//   blocks 32..159 : zx-GEMM chunk L (skip at L==NCH), writes zx buf L&1
__global__ __launch_bounds__(512, 1) void k_fused(const int*  __restrict__ tokens,
                                                  const bf16* __restrict__ eb,
                                                  const bf16* __restrict__ wit,
                                                  const float* __restrict__ rdq,
                                                  const signed char* __restrict__ whq,
                                                  const float* __restrict__ dq,
                                                  const float* __restrict__ bh,
                                                  float* __restrict__ cst,
                                                  float* __restrict__ hst,
                                                  int* __restrict__ zxqA,
                                                  int* __restrict__ zxqB,
                                                  int L) {
  __shared__ char smem[16384];
  int bid = blockIdx.x;

  if (bid < 32) {
    // ================= scan role: chunk L-1 =================
    if (L == 0) return;
    signed char* aF0 = (signed char*)smem;           // 4 KB A-frag buf 0
    signed char* aF1 = (signed char*)(smem + 4096);  // 4 KB A-frag buf 1
    const int* __restrict__ zxq = ((L - 1) & 1) ? zxqB : zxqA;
    int t0 = (L - 1) * CH;

    int p   = bid;               // batches {2p, 2p+1}
    int tid = threadIdx.x;
    int l   = tid & 63;
    int wv  = tid >> 6;
    int l4  = l >> 4;

    // register-resident Wh i8 B-fragments, gate-aligned n-tile assignment
    i32x4 w[8][4];
#pragma unroll
    for (int j = 0; j < 8; ++j) {
      int nt = (j >> 1) * 16 + wv + 8 * (j & 1);
#pragma unroll
      for (int kq = 0; kq < 4; ++kq)
        w[j][kq] = *(const i32x4*)&whq[((nt * 4 + kq) * 64 + l) * 16];
    }
#pragma unroll
    for (int j = 0; j < 8; ++j)
#pragma unroll
      for (int kq = 0; kq < 4; ++kq)
        asm volatile("" : "+v"(w[j][kq]));

    i32x4 czero = (i32x4)0;
    asm volatile("" : "+v"(czero));

    // gate-side identity (lanes 0..15 own cells; others idle in gate phase)
    int ll = l & 15;
    int u0 = wv * 16 + ll;          // gs = 0
    int u1 = (wv + 8) * 16 + ll;    // gs = 1
    float dqv[2][4], bhv[2][4];
#pragma unroll
    for (int q = 0; q < 4; ++q) {
      dqv[0][q] = dq[q * 256 + u0]; bhv[0][q] = bh[q * 256 + u0];
      dqv[1][q] = dq[q * 256 + u1]; bhv[1][q] = bh[q * 256 + u1];
    }
    int kq0 = u0 >> 6, lg0 = (u0 >> 4) & 3;
    int kq1 = u1 >> 6, lg1 = (u1 >> 4) & 3;

    float c[4];
#pragma unroll
    for (int gs = 0; gs < 2; ++gs)
#pragma unroll
      for (int bb = 0; bb < 2; ++bb)
        c[gs * 2 + bb] = (t0 == 0) ? 0.f
                       : cst[(p * 2 + bb) * 256 + (gs ? u1 : u0)];

    // zero both A-frag buffers (pad rows 2..15 stay zero forever)
    ((i32x4*)smem)[tid] = (i32x4)0;
    __syncthreads();
    if (t0 != 0 && l4 == 0) {
#pragma unroll
      for (int gs = 0; gs < 2; ++gs)
#pragma unroll
        for (int bb = 0; bb < 2; ++bb) {
          float hv = hst[(p * 2 + bb) * 256 + (gs ? u1 : u0)];
          aF0[(gs ? kq1 : kq0) * 1024 + (bb + 16 * (gs ? lg1 : lg0)) * 16 + l] =
              (signed char)(int)rintf(hv * 127.f);
        }
    }
    __syncthreads();

    // zx base; depth-2 preload (steps 0 and 1), lanes 0..15 only
    const int* zg = zxq + (size_t)(p * CH) * 2048;
    i32x4 zxA[4], zxB[4];
    if (l4 == 0) {
#pragma unroll
      for (int gs = 0; gs < 2; ++gs)
#pragma unroll
        for (int bb = 0; bb < 2; ++bb) {
          zxA[bb * 2 + gs] = *(const i32x4*)(zg + bb * 1024 + (gs ? u1 : u0) * 4);
          zxB[bb * 2 + gs] = *(const i32x4*)(zg + 2048 + bb * 1024 + (gs ? u1 : u0) * 4);
        }
    }

    for (int lt = 0; lt < CH; lt += 2) {
      LSTM_STEP(zxA, aF0, aF1, lt)
      LSTM_STEP(zxB, aF1, aF0, lt + 1)
    }

    if (l4 == 0) {
#pragma unroll
      for (int gs = 0; gs < 2; ++gs)
#pragma unroll
        for (int bb = 0; bb < 2; ++bb)
          cst[(p * 2 + bb) * 256 + (gs ? u1 : u0)] = c[gs * 2 + bb];
    }

  } else {
    // ================= gemm role: chunk L =================
    if (L >= NCH) return;
    int* __restrict__ zxw = (L & 1) ? zxqB : zxqA;
    int t0 = L * CH;
    int hh   = threadIdx.x >> 8;          // half 0/1
    int tid2 = threadIdx.x & 255;
    bf16* As = (bf16*)(smem + hh * 8192);
    bf16* Bs = (bf16*)(smem + hh * 8192 + 4096);

    int lane = tid2 & 63, wave = tid2 >> 6;
    int wm   = wave >> 1, wn = wave & 1;
    int srow = tid2 >> 2;          // batch 0..63
    int skg  = tid2 & 3;
    bf16* as_dst = &As[(skg * 64 + srow) * 8];
    bf16* bs_dst = &Bs[(skg * 64 + srow) * 8];

    for (int it = 0; it < 16; ++it) {
      int tg = ((bid - 32) + it * 128) * 2 + hh;   // 0..4095
      int mb = tg >> 4;            // step within chunk
      int nb = tg & 15;
      int n0 = nb * 64;

      long trow = (long)tokens[srow * NT + t0 + mb] * ND;
      const bf16* ap = eb  + trow + skg * 8;
      const bf16* bp = wit + (long)(n0 + srow) * ND + skg * 8;

      f32x4 acc[2][2] = {};
      for (int k0 = 0; k0 < ND; k0 += 32) {
        __syncthreads();
        *(u32x4*)as_dst = *(const u32x4*)(ap + k0);
        *(u32x4*)bs_dst = *(const u32x4*)(bp + k0);
        __syncthreads();
        short8 a0 = *(const short8*)&As[((lane >> 4) * 64 + wm * 32 +  0 + (lane & 15)) * 8];
        short8 a1 = *(const short8*)&As[((lane >> 4) * 64 + wm * 32 + 16 + (lane & 15)) * 8];
        short8 b0 = *(const short8*)&Bs[((lane >> 4) * 64 + wn * 32 +  0 + (lane & 15)) * 8];
        short8 b1 = *(const short8*)&Bs[((lane >> 4) * 64 + wn * 32 + 16 + (lane & 15)) * 8];
        acc[0][0] = __builtin_amdgcn_mfma_f32_16x16x32_bf16(a0, b0, acc[0][0], 0, 0, 0);
        acc[0][1] = __builtin_amdgcn_mfma_f32_16x16x32_bf16(a0, b1, acc[0][1], 0, 0, 0);
        acc[1][0] = __builtin_amdgcn_mfma_f32_16x16x32_bf16(a1, b0, acc[1][0], 0, 0, 0);
        acc[1][1] = __builtin_amdgcn_mfma_f32_16x16x32_bf16(a1, b1, acc[1][1], 0, 0, 0);
      }

      int cb  = n0 + wn * 32 + (lane & 15);
      float rq0 = rdq[cb], rq1 = rdq[cb + 16];
      int bb = wm * 32 + (lane >> 4) * 4;
#pragma unroll
      for (int fm = 0; fm < 2; ++fm) {
#pragma unroll
        for (int fn = 0; fn < 2; ++fn) {
          int col = cb + fn * 16;
          int uu  = col & 255, q = col >> 8;
          float rq = fn ? rq1 : rq0;
#pragma unroll
          for (int i2 = 0; i2 < 4; ++i2) {
            int rr = bb + fm * 16 + i2;
            int p0 = rr >> 1;
            size_t idx = (((size_t)(p0 * CH) + mb) * 2 + (rr & 1)) * 1024 + uu * 4 + q;
            zxw[idx] = (int)rintf(acc[fm][fn][i2] * rq);
          }
        }
      }
    }
  }
}

// ---------------- y = h @ Wo + bo ----------------
__global__ __launch_bounds__(64) void k_out(const float* __restrict__ hfin,
                                            const float* __restrict__ wo,
                                            const float* __restrict__ bo,
                                            float* __restrict__ y) {
  __shared__ float hsm[256];
  int b = blockIdx.x, tid = threadIdx.x;
  for (int i = tid; i < 256; i += 64) hsm[i] = hfin[b * 256 + i];
  __syncthreads();
  if (tid < NCLS) {
    float s = bo[tid];
    for (int k = 0; k < 256; ++k) s += hsm[k] * wo[k * NCLS + tid];
    y[b * NCLS + tid] = s;
  }
}

// ---------------- launcher ----------------
extern "C" void kernel_launch(void* const* d_in, const int* in_sizes, int n_in,
                              void* d_out, int out_size, void* d_ws, size_t ws_size,
                              hipStream_t stream) {
  const int*   tokens = (const int*)d_in[0];
  const float* embed  = (const float*)d_in[3];
  const float* wi     = (const float*)d_in[4];
  const float* wh     = (const float*)d_in[5];
  const float* bh     = (const float*)d_in[6];
  const float* wo     = (const float*)d_in[7];
  const float* bo     = (const float*)d_in[8];
  float* y = (float*)d_out;

  char* ws = (char*)d_ws;
  bf16* eb         = (bf16*)ws;        ws += (size_t)NV * ND * 2;    // 16.38 MB
  bf16* wit        = (bf16*)ws;        ws += (size_t)NH4 * ND * 2;   // 0.5 MB
  signed char* whq = (signed char*)ws; ws += (size_t)ND * NH4;       // 0.25 MB
  float* dqv       = (float*)ws;       ws += (size_t)NH4 * 4;        // 4 KB
  float* rdq       = (float*)ws;       ws += (size_t)NH4 * 4;        // 4 KB
  float* rw        = (float*)ws;       ws += (size_t)NH4 * 4;        // 4 KB
  float* cst       = (float*)ws;       ws += (size_t)NB * ND * 4;    // 64 KB
  float* hst       = (float*)ws;       ws += (size_t)NB * ND * 4;    // 64 KB
  int* zxqA        = (int*)ws;         ws += (size_t)CH * 262144;    // 64 MB
  int* zxqB        = (int*)ws;         ws += (size_t)CH * 262144;    // 64 MB

  hipLaunchKernelGGL(k_cvt_embed, dim3(NV * ND / 4 / 256), dim3(256), 0, stream, embed, eb);
  hipLaunchKernelGGL(k_cvt_wi,    dim3(NH4 * ND / 256), dim3(256), 0, stream, wi, wit);
  hipLaunchKernelGGL(k_scale,     dim3(4), dim3(256), 0, stream, wh, dqv, rdq, rw);
  hipLaunchKernelGGL(k_cvt_whq,   dim3(1024), dim3(256), 0, stream, wh, rw, whq);

  for (int L = 0; L <= NCH; ++L) {
    hipLaunchKernelGGL(k_fused, dim3(160), dim3(512), 0, stream,
                       tokens, eb, wit, rdq, whq, dqv, bh, cst, hst,
                       zxqA, zxqB, L);
  }
  hipLaunchKernelGGL(k_out, dim3(NB), dim3(64), 0, stream, hst, wo, bo, y);
}

// Round 17
// 2159.753 us; speedup vs baseline: 1.2678x; 1.2678x over previous
//
#include <hip/hip_runtime.h>
#include <hip/hip_bf16.h>
#include <stdint.h>

typedef __hip_bfloat16 bf16;
typedef __attribute__((ext_vector_type(8))) short short8;
typedef __attribute__((ext_vector_type(4))) float f32x4;
typedef __attribute__((ext_vector_type(4))) int i32x4;
typedef __attribute__((ext_vector_type(4))) unsigned int u32x4;

#define NB   64
#define NT   2048
#define NV   32000
#define ND   256
#define NH4  1024
#define NCLS 27
#define CH   256          // time chunk (double-buffered)
#define NCH  (NT / CH)    // 8

// ---------------- dtype conversion / packing ----------------

__global__ __launch_bounds__(256) void k_cvt_embed(const float* __restrict__ e,
                                                   bf16* __restrict__ o) {
  int i = blockIdx.x * blockDim.x + threadIdx.x;
  float4 v = reinterpret_cast<const float4*>(e)[i];
  union { bf16 h[4]; uint2 u; } pk;
  pk.h[0] = __float2bfloat16(v.x);
  pk.h[1] = __float2bfloat16(v.y);
  pk.h[2] = __float2bfloat16(v.z);
  pk.h[3] = __float2bfloat16(v.w);
  reinterpret_cast<uint2*>(o)[i] = pk.u;
}

// Wi [256][1024] f32 -> Wi_t [1024][256] bf16
__global__ __launch_bounds__(256) void k_cvt_wi(const float* __restrict__ wi,
                                                bf16* __restrict__ wit) {
  int i = blockIdx.x * blockDim.x + threadIdx.x;
  int col = i >> 8;
  int k   = i & 255;
  wit[i] = __float2bfloat16(wi[k * NH4 + col]);
}

// per-column scales for i8 quantization of Wh.
__global__ __launch_bounds__(256) void k_scale(const float* __restrict__ wh,
                                               float* __restrict__ dq,
                                               float* __restrict__ rdq,
                                               float* __restrict__ rw) {
  int col = blockIdx.x * 256 + threadIdx.x;   // grid 4
  float m = 0.f;
  for (int k = 0; k < ND; ++k) m = fmaxf(m, fabsf(wh[k * NH4 + col]));
  dq[col]  = m * (1.f / 16129.f);
  rdq[col] = 16129.f / m;
  rw[col]  = 127.f / m;
}

// Wh -> i8 B-fragments for mfma_i32_16x16x64_i8
__global__ __launch_bounds__(256) void k_cvt_whq(const float* __restrict__ wh,
                                                 const float* __restrict__ rw,
                                                 signed char* __restrict__ whq) {
  int idx  = blockIdx.x * 256 + threadIdx.x;  // grid 1024
  int ii   = idx & 15;
  int lane = (idx >> 4) & 63;
  int kq   = (idx >> 10) & 3;
  int nt   = idx >> 12;
  int k   = kq * 64 + (lane >> 4) * 16 + ii;
  int col = nt * 16 + (lane & 15);
  whq[idx] = (signed char)(int)rintf(wh[k * NH4 + col] * rw[col]);
}

// ---------------- gate helpers ----------------
__device__ __forceinline__ float sigf(float x) {
  return __builtin_amdgcn_rcpf(1.f + __expf(-x));
}
__device__ __forceinline__ float tanh_fast(float x) {
  return 1.f - 2.f * __builtin_amdgcn_rcpf(1.f + __expf(2.f * x));
}

#define LSTM_STEP(ZX, ST)                                                       \
  {                                                                             \
    i32x4 a0 = *(const i32x4*)&aF[0 * 1024 + l * 16];                           \
    i32x4 a1 = *(const i32x4*)&aF[1 * 1024 + l * 16];                           \
    i32x4 a2 = *(const i32x4*)&aF[2 * 1024 + l * 16];                           \
    i32x4 a3 = *(const i32x4*)&aF[3 * 1024 + l * 16];                           \
    i32x4 acc[8];                                                               \
    _Pragma("unroll")                                                           \
    for (int j = 0; j < 8; ++j) {                                               \
      i32x4 t;                                                                  \
      t = __builtin_amdgcn_mfma_i32_16x16x64_i8(a0, w[j][0], czero, 0, 0, 0);   \
      t = __builtin_amdgcn_mfma_i32_16x16x64_i8(a1, w[j][1], t, 0, 0, 0);       \
      t = __builtin_amdgcn_mfma_i32_16x16x64_i8(a2, w[j][2], t, 0, 0, 0);       \
      acc[j] = __builtin_amdgcn_mfma_i32_16x16x64_i8(a3, w[j][3], t, 0, 0, 0);  \
    }                                                                           \
    if (l4 == 0) {                                                              \
      _Pragma("unroll")                                                         \
      for (int j = 0; j < 8; ++j) {                                             \
        int col = (wv * 8 + j) * 16 + l15;                                      \
        int tt  = ((col & 255) << 2) | (col >> 8);                              \
        zl[tt]        = acc[j][0];                                              \
        zl[1024 + tt] = acc[j][1];                                              \
      }                                                                         \
    }                                                                           \
    __syncthreads();                                                            \
    {                                                                           \
      i32x4 zr = *(const i32x4*)&zl[b * 1024 + u * 4];                          \
      int s0 = zr[0] + ZX[0];                                                   \
      int s1 = zr[1] + ZX[1];                                                   \
      int s2 = zr[2] + ZX[2];                                                   \
      int s3 = zr[3] + ZX[3];                                                   \
      if ((ST) + 2 < CH)                                                        \
        ZX = *(const i32x4*)(zg + (size_t)((ST) + 2) * 2048);                   \
      float zi = (float)s0 * dqv[0] + bhv[0];                                   \
      float zf = (float)s1 * dqv[1] + bhv[1];                                   \
      float zg_ = (float)s2 * dqv[2] + bhv[2];                                  \
      float zo = (float)s3 * dqv[3] + bhv[3];                                   \
      c = sigf(zf) * c + sigf(zi) * tanh_fast(zg_);                             \
      float h = sigf(zo) * tanh_fast(c);                                        \
      aF[kqu * 1024 + (b | (lgu << 4)) * 16 + iiu] =                            \
          (signed char)(int)rintf(h * 127.f);                                   \
      if ((ST) == CH - 1) hst[(p * 2 + b) * 256 + u] = h;                       \
    }                                                                           \
    __syncthreads();                                                            \
  }

// ---------------- fused pipelined kernel ----------------
// Launch L (L = 0..NCH):
//   blocks 0..31   : LSTM-scan chunk L-1 (skip at L==0), reads zx buf (L-1)&1
//   blocks 32..159 : zx-GEMM chunk L (skip at L==NCH), writes zx buf L&1
// Roles touch disjoint buffers; visibility across launches is kernel-boundary.
// Scan blocks are fully independent (no co-residency requirement).
__global__ __launch_bounds__(512, 1) void k_fused(const int*  __restrict__ tokens,
                                                  const bf16* __restrict__ eb,
                                                  const bf16* __restrict__ wit,
                                                  const float* __restrict__ rdq,
                                                  const signed char* __restrict__ whq,
                                                  const float* __restrict__ dq,
                                                  const float* __restrict__ bh,
                                                  float* __restrict__ cst,
                                                  float* __restrict__ hst,
                                                  int* __restrict__ zxqA,
                                                  int* __restrict__ zxqB,
                                                  int L) {
  __shared__ char smem[16384];
  int bid = blockIdx.x;

  if (bid < 32) {
    // ================= scan role: chunk L-1 =================
    if (L == 0) return;
    int* zl = (int*)smem;                           // [b][u*4+q] i32, 8 KB
    signed char* aF = (signed char*)(smem + 8192);  // [kq][la][16] i8, 4 KB
    const int* __restrict__ zxq = ((L - 1) & 1) ? zxqB : zxqA;
    int t0 = (L - 1) * CH;

    int p   = bid;               // batches {2p, 2p+1}
    int tid = threadIdx.x;
    int l   = tid & 63;
    int wv  = tid >> 6;
    int l15 = l & 15, l4 = l >> 4;
    int u   = tid & 255;         // gate-phase unit
    int b   = tid >> 8;          // gate-phase batch 0/1

    // register-resident Wh i8 B-fragments (static indices only)
    i32x4 w[8][4];
#pragma unroll
    for (int j = 0; j < 8; ++j) {
      int nt = wv * 8 + j;
#pragma unroll
      for (int kq = 0; kq < 4; ++kq)
        w[j][kq] = *(const i32x4*)&whq[((nt * 4 + kq) * 64 + l) * 16];
    }
#pragma unroll
    for (int j = 0; j < 8; ++j)
#pragma unroll
      for (int kq = 0; kq < 4; ++kq)
        asm volatile("" : "+v"(w[j][kq]));

    i32x4 czero = (i32x4)0;
    asm volatile("" : "+v"(czero));

    float dqv[4], bhv[4];
#pragma unroll
    for (int q = 0; q < 4; ++q) { dqv[q] = dq[q * 256 + u]; bhv[q] = bh[q * 256 + u]; }
    float c = (t0 == 0) ? 0.f : cst[(p * 2 + b) * 256 + u];

    int kqu = u >> 6, lgu = (u >> 4) & 3, iiu = u & 15;

    if (tid < 256) ((i32x4*)aF)[tid] = (i32x4)0;
    __syncthreads();
    if (t0 != 0) {
      int hq = (int)rintf(hst[(p * 2 + b) * 256 + u] * 127.f);
      aF[kqu * 1024 + (b | (lgu << 4)) * 16 + iiu] = (signed char)hq;
    }
    __syncthreads();

    // per-thread zx base; depth-2 preload
    const int* zg = zxq + ((size_t)(p * CH) * 2 + b) * 1024 + u * 4;
    i32x4 zxA = *(const i32x4*)zg;
    i32x4 zxB = *(const i32x4*)(zg + 2048);

    for (int lt = 0; lt < CH; lt += 2) {
      LSTM_STEP(zxA, lt)
      LSTM_STEP(zxB, lt + 1)
    }

    cst[(p * 2 + b) * 256 + u] = c;

  } else {
    // ================= gemm role: chunk L =================
    if (L >= NCH) return;
    int* __restrict__ zxw = (L & 1) ? zxqB : zxqA;
    int t0 = L * CH;
    int hh   = threadIdx.x >> 8;          // half 0/1
    int tid2 = threadIdx.x & 255;
    bf16* As = (bf16*)(smem + hh * 8192);
    bf16* Bs = (bf16*)(smem + hh * 8192 + 4096);

    int lane = tid2 & 63, wave = tid2 >> 6;
    int wm   = wave >> 1, wn = wave & 1;
    int srow = tid2 >> 2;          // batch 0..63
    int skg  = tid2 & 3;
    bf16* as_dst = &As[(skg * 64 + srow) * 8];
    bf16* bs_dst = &Bs[(skg * 64 + srow) * 8];

    for (int it = 0; it < 16; ++it) {
      int tg = ((bid - 32) + it * 128) * 2 + hh;   // 0..4095
      int mb = tg >> 4;            // step within chunk
      int nb = tg & 15;
      int n0 = nb * 64;

      long trow = (long)tokens[srow * NT + t0 + mb] * ND;
      const bf16* ap = eb  + trow + skg * 8;
      const bf16* bp = wit + (long)(n0 + srow) * ND + skg * 8;

      f32x4 acc[2][2] = {};
      for (int k0 = 0; k0 < ND; k0 += 32) {
        __syncthreads();
        *(u32x4*)as_dst = *(const u32x4*)(ap + k0);
        *(u32x4*)bs_dst = *(const u32x4*)(bp + k0);
        __syncthreads();
        short8 a0 = *(const short8*)&As[((lane >> 4) * 64 + wm * 32 +  0 + (lane & 15)) * 8];
        short8 a1 = *(const short8*)&As[((lane >> 4) * 64 + wm * 32 + 16 + (lane & 15)) * 8];
        short8 b0 = *(const short8*)&Bs[((lane >> 4) * 64 + wn * 32 +  0 + (lane & 15)) * 8];
        short8 b1 = *(const short8*)&Bs[((lane >> 4) * 64 + wn * 32 + 16 + (lane & 15)) * 8];
        acc[0][0] = __builtin_amdgcn_mfma_f32_16x16x32_bf16(a0, b0, acc[0][0], 0, 0, 0);
        acc[0][1] = __builtin_amdgcn_mfma_f32_16x16x32_bf16(a0, b1, acc[0][1], 0, 0, 0);
        acc[1][0] = __builtin_amdgcn_mfma_f32_16x16x32_bf16(a1, b0, acc[1][0], 0, 0, 0);
        acc[1][1] = __builtin_amdgcn_mfma_f32_16x16x32_bf16(a1, b1, acc[1][1], 0, 0, 0);
      }

      int cb  = n0 + wn * 32 + (lane & 15);
      float rq0 = rdq[cb], rq1 = rdq[cb + 16];
      int bb = wm * 32 + (lane >> 4) * 4;
#pragma unroll
      for (int fm = 0; fm < 2; ++fm) {
#pragma unroll
        for (int fn = 0; fn < 2; ++fn) {
          int col = cb + fn * 16;
          int uu  = col & 255, q = col >> 8;
          float rq = fn ? rq1 : rq0;
#pragma unroll
          for (int i2 = 0; i2 < 4; ++i2) {
            int rr = bb + fm * 16 + i2;
            int p0 = rr >> 1;
            size_t idx = (((size_t)(p0 * CH) + mb) * 2 + (rr & 1)) * 1024 + uu * 4 + q;
            zxw[idx] = (int)rintf(acc[fm][fn][i2] * rq);
          }
        }
      }
    }
  }
}

// ---------------- y = h @ Wo + bo ----------------
__global__ __launch_bounds__(64) void k_out(const float* __restrict__ hfin,
                                            const float* __restrict__ wo,
                                            const float* __restrict__ bo,
                                            float* __restrict__ y) {
  __shared__ float hsm[256];
  int b = blockIdx.x, tid = threadIdx.x;
  for (int i = tid; i < 256; i += 64) hsm[i] = hfin[b * 256 + i];
  __syncthreads();
  if (tid < NCLS) {
    float s = bo[tid];
    for (int k = 0; k < 256; ++k) s += hsm[k] * wo[k * NCLS + tid];
    y[b * NCLS + tid] = s;
  }
}

// ---------------- launcher ----------------
extern "C" void kernel_launch(void* const* d_in, const int* in_sizes, int n_in,
                              void* d_out, int out_size, void* d_ws, size_t ws_size,
                              hipStream_t stream) {
  const int*   tokens = (const int*)d_in[0];
  const float* embed  = (const float*)d_in[3];
  const float* wi     = (const float*)d_in[4];
  const float* wh     = (const float*)d_in[5];
  const float* bh     = (const float*)d_in[6];
  const float* wo     = (const float*)d_in[7];
  const float* bo     = (const float*)d_in[8];
  float* y = (float*)d_out;

  char* ws = (char*)d_ws;
  bf16* eb         = (bf16*)ws;        ws += (size_t)NV * ND * 2;    // 16.38 MB
  bf16* wit        = (bf16*)ws;        ws += (size_t)NH4 * ND * 2;   // 0.5 MB
  signed char* whq = (signed char*)ws; ws += (size_t)ND * NH4;       // 0.25 MB
  float* dqv       = (float*)ws;       ws += (size_t)NH4 * 4;        // 4 KB
  float* rdq       = (float*)ws;       ws += (size_t)NH4 * 4;        // 4 KB
  float* rw        = (float*)ws;       ws += (size_t)NH4 * 4;        // 4 KB
  float* cst       = (float*)ws;       ws += (size_t)NB * ND * 4;    // 64 KB
  float* hst       = (float*)ws;       ws += (size_t)NB * ND * 4;    // 64 KB
  int* zxqA        = (int*)ws;         ws += (size_t)CH * 262144;    // 64 MB
  int* zxqB        = (int*)ws;         ws += (size_t)CH * 262144;    // 64 MB

  hipLaunchKernelGGL(k_cvt_embed, dim3(NV * ND / 4 / 256), dim3(256), 0, stream, embed, eb);
  hipLaunchKernelGGL(k_cvt_wi,    dim3(NH4 * ND / 256), dim3(256), 0, stream, wi, wit);
  hipLaunchKernelGGL(k_scale,     dim3(4), dim3(256), 0, stream, wh, dqv, rdq, rw);
  hipLaunchKernelGGL(k_cvt_whq,   dim3(1024), dim3(256), 0, stream, wh, rw, whq);

  for (int L = 0; L <= NCH; ++L) {
    hipLaunchKernelGGL(k_fused, dim3(160), dim3(512), 0, stream,
                       tokens, eb, wit, rdq, whq, dqv, bh, cst, hst,
                       zxqA, zxqB, L);
  }
  hipLaunchKernelGGL(k_out, dim3(NB), dim3(64), 0, stream, hst, wo, bo, y);
}